// Round 17
// baseline (151.665 us; speedup 1.0000x reference)
//
#include <hip/hip_runtime.h>
#include <math.h>

#define C 128
#define BIAS 256.0f

typedef __attribute__((ext_vector_type(8))) short short8;     // 8 bf16 (4 VGPRs)
typedef __attribute__((ext_vector_type(4))) float f32x4;
typedef __attribute__((ext_vector_type(4))) unsigned int uint4v;
typedef unsigned short u16;
typedef unsigned int u32;
typedef unsigned long long u64;

static __device__ __forceinline__ u16 f2bf(float f) {
  unsigned int u = __builtin_bit_cast(unsigned int, f);
  unsigned int r = (u + 0x7fffu + ((u >> 16) & 1u)) >> 16;
  return (u16)r;
}

static __device__ __forceinline__ float bf2f(short s) {
  return __uint_as_float(((u32)(u16)s) << 16);
}

// async global->LDS, 16B per lane; LDS dest = wave-uniform base + lane*16
static __device__ __forceinline__ void gload_lds16(const void* g, void* l) {
  __builtin_amdgcn_global_load_lds(
      (const __attribute__((address_space(1))) unsigned int*)g,
      (__attribute__((address_space(3))) unsigned int*)l, 16, 0, 0);
}

// ---------------------------------------------------------------------------
// K0: fused fp32->bf16 convert (+ bank scaled by -2) + row norms + packed
// sentinel init + rescore completion-counter zeroing.
// ---------------------------------------------------------------------------
__global__ __launch_bounds__(256) void prep_kernel(
    const float* __restrict__ emb, const float* __restrict__ bank,
    u16* __restrict__ Abf, u16* __restrict__ Bbf, float* __restrict__ anorm,
    float* __restrict__ bnorm, u64* __restrict__ packed, int* __restrict__ cnt,
    int N, int M) {
  const int tid = threadIdx.x;
  const int chunk = blockIdx.x * 256 + tid;
  const int total = (N + M) * (C / 8);
  if (chunk >= total) return;
  if (chunk < N) packed[chunk] = ~0ull;   // fresh sentinel every launch
  if (chunk < 16) cnt[chunk] = 0;         // rescore completion counters
  const int gr = chunk >> 4;              // 16 chunks per 128-elem row
  const int co = (chunk & 15) * 8;
  const float* src;
  u16* dst;
  float* ndst;
  int r;
  float sc;
  if (gr < N) { src = emb; dst = Abf; ndst = anorm; r = gr; sc = 1.0f; }
  else { src = bank; dst = Bbf; ndst = bnorm; r = gr - N; sc = -2.0f; }
  const float* p = src + (size_t)r * C + co;
  float4 v0 = *(const float4*)p;
  float4 v1 = *(const float4*)(p + 4);
  u16 o[8] = {f2bf(sc * v0.x), f2bf(sc * v0.y), f2bf(sc * v0.z),
              f2bf(sc * v0.w), f2bf(sc * v1.x), f2bf(sc * v1.y),
              f2bf(sc * v1.z), f2bf(sc * v1.w)};
  *(uint4v*)(dst + (size_t)r * C + co) = *(const uint4v*)o;
  float s = v0.x * v0.x + v0.y * v0.y + v0.z * v0.z + v0.w * v0.w +
            v1.x * v1.x + v1.y * v1.y + v1.z * v1.z + v1.w * v1.w;
#pragma unroll
  for (int m = 1; m <= 8; m <<= 1) s += __shfl_xor(s, m, 64);
  if ((tid & 15) == 0) ndst[r] = s;
}

// ---------------------------------------------------------------------------
// K1: MFMA NN search.  grid 1568 = 98 row-tiles x 16 j-subchunks; sub&7 ==
// XCD id.  Wave grid 2x2: each wave = 64 DISTINCT-col-half rows?? no —
// wave (wr,wc) owns rows [wr*64, wr*64+64) x cols [wc*32, wc*32+32):
// B-fragment LDS reads per wave drop 16 -> 8 per tile (r16 analysis: the
// old 1x4 mapping had all 4 waves reading IDENTICAL B fragments -> LDS
// read throughput 31us > MFMA 25us = the real bottleneck).  af[4][4] =
// 64 VGPR static; persistent regs ~112 <= 128 @ 4 blocks/CU.
// B 64-col tiles via global_load_lds w16, double-buffered 2x16KB,
// both-sides XOR swizzle.  acc init = bnorm[col]+BIAS; Bbf pre-scaled by
// -2 -> MFMA output = bn+BIAS-2dot.  Argmin: packed u32 key
// (bits&~0x3FFF)|col, running v_min_u32, folded over the wave's 2 fj cols.
// NOTE (r14): never raise launch_bounds waves — VGPR 32 => 458MB spills.
// NOTE (r7): never put two DIFFERENT bank-eighths on one XCD — L2 thrash.
// NOTE (r16): grid finer than 1568 loses to per-block fixed costs.
// ---------------------------------------------------------------------------
__global__ __launch_bounds__(256, 4) void nn_mfma(
    const u16* __restrict__ Abf, const u16* __restrict__ Bbf,
    const float* __restrict__ bnorm, const float* __restrict__ anorm,
    u64* __restrict__ packed, int N, int M) {
  __shared__ short Bs[2][8192];        // 2 x 16KB
  const int tid = threadIdx.x;
  const int lane = tid & 63;
  const int w = tid >> 6;
  const int wr = w >> 1, wc = w & 1;   // 2x2 wave grid
  const int lr = lane & 15, kg = lane >> 4;
  const int bid = blockIdx.x;
  const int sub = bid & 15;            // sub&7 == XCD id
  const int row0 = (bid >> 4) * 128;
  const int j0base = (sub & 7) * (M >> 3) + (sub >> 3) * (M >> 4);

  int soff[4];
#pragma unroll
  for (int q = 0; q < 4; ++q) {
    const int r = q * 16 + (tid >> 4);
    const int c = (((tid & 15) * 16) ^ ((r & 7) << 4)) >> 1;
    soff[q] = r * C + c;
  }

#define STAGE(bufi, jj)                                                     \
  do {                                                                      \
    const u16* gsrc = Bbf + (size_t)(jj) * C;                               \
    _Pragma("unroll") for (int q = 0; q < 4; ++q)                           \
        gload_lds16(gsrc + soff[q], &Bs[bufi][q * 2048 + w * 512]);         \
  } while (0)

  // A fragments straight from global (once; L2-resident per XCD).
  // 64 rows per wave: af[fi][k], fi in 0..3.
  short8 af[4][4];
  {
    const u16* pa = Abf + (size_t)(row0 + wr * 64 + lr) * C + kg * 8;
#pragma unroll
    for (int fi = 0; fi < 4; ++fi)
#pragma unroll
      for (int k = 0; k < 4; ++k)
        af[fi][k] = *(const short8*)(pa + fi * 16 * C + k * 32);
  }

  u32 minv[16];
#pragma unroll
  for (int s = 0; s < 16; ++s) minv[s] = 0xFFFFFFFFu;

  STAGE(0, j0base);
  __syncthreads();                     // tile 0 resident

  int j0 = j0base;
  for (int t = 0; t < 16; ++t) {
    const int buf = t & 1;
    if (t < 15) STAGE(buf ^ 1, j0 + 64);   // async; flies under compute

    const float bnb0 = bnorm[j0 + wc * 32 + lr] + BIAS;
    const float bnb1 = bnorm[j0 + wc * 32 + 16 + lr] + BIAS;

    f32x4 acc[4][2];
#pragma unroll
    for (int fi = 0; fi < 4; ++fi) {
      acc[fi][0] = (f32x4){bnb0, bnb0, bnb0, bnb0};
      acc[fi][1] = (f32x4){bnb1, bnb1, bnb1, bnb1};
    }

    const short* bsb = &Bs[buf][0];
    const int cxor = (lr & 7) << 3;    // short-index XOR = byte XOR <<4
#pragma unroll
    for (int k = 0; k < 4; ++k) {
      const int ko = (k * 32 + kg * 8) ^ cxor;
      short8 bf0 = *(const short8*)&bsb[(wc * 32 + lr) * C + ko];
      short8 bf1 = *(const short8*)&bsb[(wc * 32 + 16 + lr) * C + ko];
#pragma unroll
      for (int fi = 0; fi < 4; ++fi)
        acc[fi][0] = __builtin_amdgcn_mfma_f32_16x16x32_bf16(
            af[fi][k], bf0, acc[fi][0], 0, 0, 0);
#pragma unroll
      for (int fi = 0; fi < 4; ++fi)
        acc[fi][1] = __builtin_amdgcn_mfma_f32_16x16x32_bf16(
            af[fi][k], bf1, acc[fi][1], 0, 0, 0);
    }

    // 2-op epilogue: key = (bits & ~0x3FFF) | col ; fold fj into minv[16]
#pragma unroll
    for (int fj = 0; fj < 2; ++fj) {
      const u32 col = (u32)(j0 + wc * 32 + fj * 16 + lr);
#pragma unroll
      for (int fi = 0; fi < 4; ++fi) {
#pragma unroll
        for (int r = 0; r < 4; ++r) {
          u32 key = (__float_as_uint(acc[fi][fj][r]) & 0xFFFFC000u) | col;
          const int s = fi * 4 + r;
          minv[s] = key < minv[s] ? key : minv[s];
        }
      }
    }
    __syncthreads();   // all waves done with buf; prefetch (t+1) arrived
    j0 += 64;
  }
#undef STAGE

  // butterfly u32-min over the 16 col-lanes (lane bits 0..3), global merge.
  // slot s: row = row0 + wr*64 + (s>>2)*16 + kg*4 + (s&3)
#pragma unroll
  for (int s = 0; s < 16; ++s) {
    u32 k = minv[s];
#pragma unroll
    for (int m = 1; m <= 8; m <<= 1) {
      u32 ok = (u32)__shfl_xor((int)k, m, 64);
      k = ok < k ? ok : k;
    }
    if (lr == 0) {
      const int row = row0 + wr * 64 + (s >> 2) * 16 + kg * 4 + (s & 3);
      const u32 col = k & 0x3FFFu;
      const float vm = __uint_as_float(k & 0xFFFFC000u);
      float d2 = fmaxf(anorm[row] + (vm - BIAS), 0.0f);
      u64 pk = ((u64)__float_as_uint(d2) << 32) | col;
      atomicMin(&packed[row], pk);
    }
  }
}

// ---------------------------------------------------------------------------
// K2: post kernel — rescore chunks (x<32) + blur octets (x>=32), one launch.
// ---------------------------------------------------------------------------
__global__ __launch_bounds__(256) void post_kernel(
    const u16* __restrict__ Bbf, const float* __restrict__ bnorm,
    const u64* __restrict__ packed, const float* __restrict__ emb,
    const float* __restrict__ Bk, float* __restrict__ score,
    int* __restrict__ maxrow, float* __restrict__ cvals,
    int* __restrict__ cidx, int* __restrict__ cnt, float* __restrict__ pred,
    float* __restrict__ out, int M) {
  const int b = blockIdx.y;
  const int tid = threadIdx.x;
  __shared__ float vecf[C];
  __shared__ float sv[256];
  __shared__ int si[256];
  __shared__ int sl[256];
  __shared__ float wv[288];
  __shared__ int wi[288];
  __shared__ int sp[256];
  __shared__ int sup[9];
  __shared__ float ds[9];

  if (blockIdx.x >= 32) {
    // ---------------- blur path: octet q = blockIdx.x - 32 ----------------
    const int q = blockIdx.x - 32;
    float* g = vecf;                    // [33]
    float (*rows)[28] = (float(*)[28]) & sv[0];   // [5][28]
    float (*gvs)[5] = (float(*)[5]) & wv[0];      // [8][5]
    const int rc0 = q < 2 ? 0 : (q > 25 ? 23 : q - 2);
    if (tid < 33) {
      float d = (float)tid - 16.0f;
      g[tid] = expf(-(d * d) * (1.0f / 32.0f));
    }
    if (tid < 140) {
      const int i = tid / 28, cc = tid - i * 28;
      u64 p = packed[(size_t)b * 784 + (rc0 + i) * 28 + cc];
      float d2 = __uint_as_float((unsigned)(p >> 32));
      rows[i][cc] = sqrtf(fmaxf(d2, 1e-12f));
    }
    __syncthreads();
    if (tid == 0) {
      float s = 0.0f;
      for (int t = 0; t < 33; ++t) s += g[t];
      ds[0] = 1.0f / (s * s);
    }
    if (tid < 40) {
      const int dy = tid / 5, i = tid - dy * 5;
      const int y = q * 8 + dy;
      float acc = 0.0f;
      for (int t = 0; t < 33; ++t) {
        int yy = y + t - 16;
        yy = yy < 0 ? -yy : (yy > 223 ? 446 - yy : yy);
        acc += ((yy >> 3) - rc0 == i) ? g[t] : 0.0f;
      }
      gvs[dy][i] = acc;
    }
    __syncthreads();
    if (tid < 224) {
      float hacc[5];
#pragma unroll
      for (int i = 0; i < 5; ++i) hacc[i] = 0.0f;
      for (int s = 0; s < 33; ++s) {
        int xx = tid + s - 16;
        xx = xx < 0 ? -xx : (xx > 223 ? 446 - xx : xx);
        const int cs = xx >> 3;
        const float gs_ = g[s];
#pragma unroll
        for (int i = 0; i < 5; ++i) hacc[i] += gs_ * rows[i][cs];
      }
      const float ginv = ds[0];
#pragma unroll
      for (int dy = 0; dy < 8; ++dy) {
        float acc = 0.0f;
#pragma unroll
        for (int i = 0; i < 5; ++i) acc += gvs[dy][i] * hacc[i];
        out[((size_t)b * 224 + q * 8 + dy) * 224 + tid] = acc * ginv;
      }
    }
    return;
  }

  // ---------------- rescore path: chunk c = blockIdx.x ----------------
  const int c = blockIdx.x;

  // argmax over packed d2 (first occurrence), every block re-derives
  {
    float bv = -INFINITY;
    int bi_ = 0x7fffffff, bl = 0;
    for (int i = tid; i < 784; i += 256) {
      u64 p = packed[(size_t)b * 784 + i];
      float v = __uint_as_float((unsigned)(p >> 32));
      if (v > bv) { bv = v; bi_ = i; bl = (int)(unsigned)p; }
    }
    sv[tid] = bv; si[tid] = bi_; sl[tid] = bl;
    __syncthreads();
    for (int s = 128; s > 0; s >>= 1) {
      if (tid < s) {
        if (sv[tid + s] > sv[tid] ||
            (sv[tid + s] == sv[tid] && si[tid + s] < si[tid])) {
          sv[tid] = sv[tid + s]; si[tid] = si[tid + s]; sl[tid] = sl[tid + s];
        }
      }
      __syncthreads();
    }
  }
  const int nn = sl[0];
  if (c == 0 && tid == 0) {
    score[b] = sqrtf(fmaxf(sv[0], 1e-12f));
    maxrow[b] = b * 784 + si[0];
  }
  __syncthreads();

  if (tid < 16) {
    short8 v = ((const short8*)(Bbf + (size_t)nn * C))[tid];
#pragma unroll
    for (int e = 0; e < 8; ++e) vecf[tid * 8 + e] = bf2f(v[e]);
  }
  __syncthreads();
  const float nnorm = bnorm[nn];
  const int j0 = c * (M >> 5);          // 512 rows per chunk
  float rv[2];
  int rj[2];
#pragma unroll
  for (int q = 0; q < 2; ++q) {
    const int j = j0 + q * 256 + tid;
    const short8* br = (const short8*)(Bbf + (size_t)j * C);
    float dot = 0.0f;
#pragma unroll
    for (int kc = 0; kc < 16; ++kc) {
      short8 v = br[kc];
      float4 w0 = *(const float4*)&vecf[kc * 8];
      float4 w1 = *(const float4*)&vecf[kc * 8 + 4];
      dot += bf2f(v[0]) * w0.x + bf2f(v[1]) * w0.y + bf2f(v[2]) * w0.z +
             bf2f(v[3]) * w0.w + bf2f(v[4]) * w1.x + bf2f(v[5]) * w1.y +
             bf2f(v[6]) * w1.z + bf2f(v[7]) * w1.w;
    }
    rv[q] = nnorm + bnorm[j] - 0.5f * dot;   // Bbf = -2*bank: dot_bf = 4*dot
    rj[q] = j;
  }
  for (int s9 = 0; s9 < 9; ++s9) {
    float bv = INFINITY;
    int bj = 0x7fffffff;
#pragma unroll
    for (int q = 0; q < 2; ++q)
      if (rv[q] < bv) { bv = rv[q]; bj = rj[q]; }
    sv[tid] = bv; si[tid] = bj;
    __syncthreads();
    for (int s = 128; s > 0; s >>= 1) {
      if (tid < s) {
        if (sv[tid + s] < sv[tid] ||
            (sv[tid + s] == sv[tid] && si[tid + s] < si[tid])) {
          sv[tid] = sv[tid + s]; si[tid] = si[tid + s];
        }
      }
      __syncthreads();
    }
    const int selj = si[0];
    if (tid == 0) {
      cvals[((size_t)b * 32 + c) * 9 + s9] = sv[0];
      cidx[((size_t)b * 32 + c) * 9 + s9] = selj;
    }
#pragma unroll
    for (int q = 0; q < 2; ++q)
      if (rj[q] == selj) rv[q] = INFINITY;
    __syncthreads();
  }

  // completion: last chunk-block for this image merges all 288 candidates
  if (tid == 0) {
    __threadfence();                    // release candidate writes
    sl[0] = atomicAdd(&cnt[b], 1);
  }
  __syncthreads();
  if (sl[0] != 31) return;
  __threadfence();                      // acquire all chunks' writes

  for (int i = tid; i < 288; i += 256) {
    wv[i] = cvals[(size_t)b * 288 + i];
    wi[i] = cidx[(size_t)b * 288 + i];
  }
  if (tid < 32)
    *(float4*)&vecf[tid * 4] =
        *(const float4*)(emb + (size_t)maxrow[b] * C + tid * 4);
  __syncthreads();
  for (int s9 = 0; s9 < 9; ++s9) {
    float bv = INFINITY;
    int bi_ = 0x7fffffff, bp = -1;
    for (int i = tid; i < 288; i += 256) {
      if (wv[i] < bv || (wv[i] == bv && wi[i] < bi_)) {
        bv = wv[i]; bi_ = wi[i]; bp = i;
      }
    }
    sv[tid] = bv; si[tid] = bi_; sp[tid] = bp;
    __syncthreads();
    for (int s = 128; s > 0; s >>= 1) {
      if (tid < s) {
        if (sv[tid + s] < sv[tid] ||
            (sv[tid + s] == sv[tid] && si[tid + s] < si[tid])) {
          sv[tid] = sv[tid + s]; si[tid] = si[tid + s]; sp[tid] = sp[tid + s];
        }
      }
      __syncthreads();
    }
    if (tid == 0) {
      sup[s9] = si[0];
      wv[sp[0]] = INFINITY;
    }
    __syncthreads();
  }
  const int w = tid >> 6, lane = tid & 63;
  for (int s = w; s < 9; s += 4) {
    const float* br = Bk + (size_t)sup[s] * C;
    float d0 = vecf[lane * 2] - br[lane * 2];
    float d1 = vecf[lane * 2 + 1] - br[lane * 2 + 1];
    float acc = d0 * d0 + d1 * d1;
#pragma unroll
    for (int m = 1; m <= 32; m <<= 1) acc += __shfl_xor(acc, m, 64);
    if (lane == 0) ds[s] = sqrtf(fmaxf(acc, 1e-12f));
  }
  __syncthreads();
  if (tid == 0) {
    float m = ds[0];
    for (int t = 1; t < 9; ++t) m = fmaxf(m, ds[t]);
    float sum = 0.0f, e0 = 0.0f;
    for (int t = 0; t < 9; ++t) {
      float e = expf(ds[t] - m);
      sum += e;
      if (t == 0) e0 = e;
    }
    pred[b] = (1.0f - e0 / sum) * score[b];
  }
}

// ---------------------------------------------------------------------------
extern "C" void kernel_launch(void* const* d_in, const int* in_sizes, int n_in,
                              void* d_out, int out_size, void* d_ws,
                              size_t ws_size, hipStream_t stream) {
  const float* emb = (const float*)d_in[0];
  const float* bank = (const float*)d_in[1];
  const int N = in_sizes[0] / C;  // 12544
  const int M = in_sizes[1] / C;  // 16384
  const int B = 16;

  u16* Abf = (u16*)d_ws;                          // N*C bf16
  u16* Bbf = Abf + (size_t)N * C;                 // M*C bf16 (scaled -2)
  u64* packed = (u64*)(Bbf + (size_t)M * C);      // N   (8B-aligned)
  float* anorm = (float*)(packed + N);            // N
  float* bnorm = anorm + N;                       // M
  float* score = bnorm + M;                       // B
  int* maxrow = (int*)(score + B);                // B
  float* cvals = (float*)(maxrow + B);            // B*288
  int* cidx = (int*)(cvals + B * 288);            // B*288
  int* cnt = cidx + B * 288;                      // B

  float* out_map = (float*)d_out;
  float* out_pred = out_map + (size_t)B * 224 * 224;

  const int total = (N + M) * (C / 8);
  prep_kernel<<<(total + 255) / 256, 256, 0, stream>>>(
      emb, bank, Abf, Bbf, anorm, bnorm, packed, cnt, N, M);
  nn_mfma<<<(N / 128) * 16, 256, 0, stream>>>(Abf, Bbf, bnorm, anorm, packed,
                                              N, M);
  post_kernel<<<dim3(60, B), 256, 0, stream>>>(Bbf, bnorm, packed, emb, bank,
                                               score, maxrow, cvals, cidx,
                                               cnt, out_pred, out_map, M);
}

// Round 18
// 122.004 us; speedup vs baseline: 1.2431x; 1.2431x over previous
//
#include <hip/hip_runtime.h>
#include <math.h>

#define C 128
#define BIAS 256.0f

typedef __attribute__((ext_vector_type(8))) short short8;     // 8 bf16 (4 VGPRs)
typedef __attribute__((ext_vector_type(4))) float f32x4;
typedef __attribute__((ext_vector_type(4))) unsigned int uint4v;
typedef unsigned short u16;
typedef unsigned int u32;
typedef unsigned long long u64;

static __device__ __forceinline__ u16 f2bf(float f) {
  unsigned int u = __builtin_bit_cast(unsigned int, f);
  unsigned int r = (u + 0x7fffu + ((u >> 16) & 1u)) >> 16;
  return (u16)r;
}

static __device__ __forceinline__ float bf2f(short s) {
  return __uint_as_float(((u32)(u16)s) << 16);
}

// async global->LDS, 16B per lane; LDS dest = wave-uniform base + lane*16
static __device__ __forceinline__ void gload_lds16(const void* g, void* l) {
  __builtin_amdgcn_global_load_lds(
      (const __attribute__((address_space(1))) unsigned int*)g,
      (__attribute__((address_space(3))) unsigned int*)l, 16, 0, 0);
}

// ---------------------------------------------------------------------------
// K0: fused fp32->bf16 convert (+ bank scaled by -2) + row norms + packed
// sentinel init + rescore completion-counter zeroing.
// ---------------------------------------------------------------------------
__global__ __launch_bounds__(256) void prep_kernel(
    const float* __restrict__ emb, const float* __restrict__ bank,
    u16* __restrict__ Abf, u16* __restrict__ Bbf, float* __restrict__ anorm,
    float* __restrict__ bnorm, u64* __restrict__ packed, int* __restrict__ cnt,
    int N, int M) {
  const int tid = threadIdx.x;
  const int chunk = blockIdx.x * 256 + tid;
  const int total = (N + M) * (C / 8);
  if (chunk >= total) return;
  if (chunk < N) packed[chunk] = ~0ull;   // fresh sentinel every launch
  if (chunk < 16) cnt[chunk] = 0;         // rescore completion counters
  const int gr = chunk >> 4;              // 16 chunks per 128-elem row
  const int co = (chunk & 15) * 8;
  const float* src;
  u16* dst;
  float* ndst;
  int r;
  float sc;
  if (gr < N) { src = emb; dst = Abf; ndst = anorm; r = gr; sc = 1.0f; }
  else { src = bank; dst = Bbf; ndst = bnorm; r = gr - N; sc = -2.0f; }
  const float* p = src + (size_t)r * C + co;
  float4 v0 = *(const float4*)p;
  float4 v1 = *(const float4*)(p + 4);
  u16 o[8] = {f2bf(sc * v0.x), f2bf(sc * v0.y), f2bf(sc * v0.z),
              f2bf(sc * v0.w), f2bf(sc * v1.x), f2bf(sc * v1.y),
              f2bf(sc * v1.z), f2bf(sc * v1.w)};
  *(uint4v*)(dst + (size_t)r * C + co) = *(const uint4v*)o;
  float s = v0.x * v0.x + v0.y * v0.y + v0.z * v0.z + v0.w * v0.w +
            v1.x * v1.x + v1.y * v1.y + v1.z * v1.z + v1.w * v1.w;
#pragma unroll
  for (int m = 1; m <= 8; m <<= 1) s += __shfl_xor(s, m, 64);
  if ((tid & 15) == 0) ndst[r] = s;
}

// ---------------------------------------------------------------------------
// K1: MFMA NN search (r15 config — measured 61.5us, MfmaUtil 35%, VGPR 64;
// reproduced r9/r11/r13/r15).  grid 1568 = 98 row-tiles x 16 j-subchunks;
// sub&7 == XCD id.  4 waves x (32 distinct rows x 64 cols); af[2][4] = 32
// VGPR/wave.  B 64-col tiles via global_load_lds w16, double-buffered
// 2x16KB, both-sides XOR swizzle.  acc init = bnorm[col]+BIAS (pipelined 1
// tile ahead); Bbf pre-scaled by -2 -> MFMA output = bn+BIAS-2dot.  Argmin:
// packed u32 key (bits&~0x3FFF)|col, running v_min_u32.  4 blocks/CU.
// NOTE (r14): never raise launch_bounds waves — VGPR 32 => 458MB spills.
// NOTE (r17): 2x2 wave grid (af[4][4]=64 regs) spills despite the 128
//   budget — allocator stays at 64 and dumps af to scratch.  Keep 1x4.
// NOTE (r7): never put two DIFFERENT bank-eighths on one XCD — L2 thrash.
// NOTE (r16): grid finer than 1568 loses to per-block fixed costs.
// NOTE (r12): counted-vmcnt 3-buffer pipeline = null (needs full 8-phase).
// ---------------------------------------------------------------------------
__global__ __launch_bounds__(256, 4) void nn_mfma(
    const u16* __restrict__ Abf, const u16* __restrict__ Bbf,
    const float* __restrict__ bnorm, const float* __restrict__ anorm,
    u64* __restrict__ packed, int N, int M) {
  __shared__ short Bs[2][8192];        // 2 x 16KB
  const int tid = threadIdx.x;
  const int lane = tid & 63;
  const int w = tid >> 6;              // wave w -> rows w*32..w*32+32
  const int lr = lane & 15, kg = lane >> 4;
  const int bid = blockIdx.x;
  const int sub = bid & 15;            // sub&7 == XCD id
  const int row0 = (bid >> 4) * 128;
  const int j0base = (sub & 7) * (M >> 3) + (sub >> 3) * (M >> 4);

  int soff[4];
#pragma unroll
  for (int q = 0; q < 4; ++q) {
    const int r = q * 16 + (tid >> 4);
    const int c = (((tid & 15) * 16) ^ ((r & 7) << 4)) >> 1;
    soff[q] = r * C + c;
  }

#define STAGE(bufi, jj)                                                     \
  do {                                                                      \
    const u16* gsrc = Bbf + (size_t)(jj) * C;                               \
    _Pragma("unroll") for (int q = 0; q < 4; ++q)                           \
        gload_lds16(gsrc + soff[q], &Bs[bufi][q * 2048 + w * 512]);         \
  } while (0)

  short8 af[2][4];
  {
    const u16* pa = Abf + (size_t)(row0 + w * 32 + lr) * C + kg * 8;
#pragma unroll
    for (int fi = 0; fi < 2; ++fi)
#pragma unroll
      for (int k = 0; k < 4; ++k)
        af[fi][k] = *(const short8*)(pa + fi * 16 * C + k * 32);
  }

  u32 minv[8];
#pragma unroll
  for (int s = 0; s < 8; ++s) minv[s] = 0xFFFFFFFFu;

  STAGE(0, j0base);

  const float* bnp = bnorm + j0base + lr;
  float bnc[4], bnn[4];
#pragma unroll
  for (int fj = 0; fj < 4; ++fj) bnc[fj] = bnp[fj * 16] + BIAS;

  __syncthreads();                     // tile 0 resident

  int j0 = j0base;
  for (int t = 0; t < 16; ++t) {
    const int buf = t & 1;
    if (t < 15) {
      STAGE(buf ^ 1, j0 + 64);         // async; flies under compute
#pragma unroll
      for (int fj = 0; fj < 4; ++fj)
        bnn[fj] = bnp[(t + 1) * 64 + fj * 16] + BIAS;
    }

    f32x4 acc[2][4];
#pragma unroll
    for (int fi = 0; fi < 2; ++fi)
#pragma unroll
      for (int fj = 0; fj < 4; ++fj)
        acc[fi][fj] = (f32x4){bnc[fj], bnc[fj], bnc[fj], bnc[fj]};

    const short* bsb = &Bs[buf][0];
    const int cxor = (lr & 7) << 3;
#pragma unroll
    for (int k = 0; k < 4; ++k) {
      const int ko = (k * 32 + kg * 8) ^ cxor;
      short8 bf[4];
#pragma unroll
      for (int fj = 0; fj < 4; ++fj)
        bf[fj] = *(const short8*)&bsb[(fj * 16 + lr) * C + ko];
#pragma unroll
      for (int fi = 0; fi < 2; ++fi)
#pragma unroll
        for (int fj = 0; fj < 4; ++fj)
          acc[fi][fj] = __builtin_amdgcn_mfma_f32_16x16x32_bf16(
              af[fi][k], bf[fj], acc[fi][fj], 0, 0, 0);
    }

#pragma unroll
    for (int fj = 0; fj < 4; ++fj) {
      const u32 col = (u32)(j0 + fj * 16 + lr);
#pragma unroll
      for (int fi = 0; fi < 2; ++fi) {
#pragma unroll
        for (int r = 0; r < 4; ++r) {
          u32 key = (__float_as_uint(acc[fi][fj][r]) & 0xFFFFC000u) | col;
          const int s = fi * 4 + r;
          minv[s] = key < minv[s] ? key : minv[s];
        }
      }
    }
#pragma unroll
    for (int fj = 0; fj < 4; ++fj) bnc[fj] = bnn[fj];
    __syncthreads();
    j0 += 64;
  }
#undef STAGE

#pragma unroll
  for (int s = 0; s < 8; ++s) {
    u32 k = minv[s];
#pragma unroll
    for (int m = 1; m <= 8; m <<= 1) {
      u32 ok = (u32)__shfl_xor((int)k, m, 64);
      k = ok < k ? ok : k;
    }
    if (lr == 0) {
      const int row = row0 + w * 32 + (s >> 2) * 16 + kg * 4 + (s & 3);
      const u32 col = k & 0x3FFFu;
      const float vm = __uint_as_float(k & 0xFFFFC000u);
      float d2 = fmaxf(anorm[row] + (vm - BIAS), 0.0f);
      u64 pk = ((u64)__float_as_uint(d2) << 32) | col;
      atomicMin(&packed[row], pk);
    }
  }
}

// ---------------------------------------------------------------------------
// K2: post kernel — rescore chunks (x<32) + blur octets (x>=32), one launch.
// ---------------------------------------------------------------------------
__global__ __launch_bounds__(256) void post_kernel(
    const u16* __restrict__ Bbf, const float* __restrict__ bnorm,
    const u64* __restrict__ packed, const float* __restrict__ emb,
    const float* __restrict__ Bk, float* __restrict__ score,
    int* __restrict__ maxrow, float* __restrict__ cvals,
    int* __restrict__ cidx, int* __restrict__ cnt, float* __restrict__ pred,
    float* __restrict__ out, int M) {
  const int b = blockIdx.y;
  const int tid = threadIdx.x;
  __shared__ float vecf[C];
  __shared__ float sv[256];
  __shared__ int si[256];
  __shared__ int sl[256];
  __shared__ float wv[288];
  __shared__ int wi[288];
  __shared__ int sp[256];
  __shared__ int sup[9];
  __shared__ float ds[9];

  if (blockIdx.x >= 32) {
    // ---------------- blur path: octet q = blockIdx.x - 32 ----------------
    const int q = blockIdx.x - 32;
    float* g = vecf;                    // [33]
    float (*rows)[28] = (float(*)[28]) & sv[0];   // [5][28]
    float (*gvs)[5] = (float(*)[5]) & wv[0];      // [8][5]
    const int rc0 = q < 2 ? 0 : (q > 25 ? 23 : q - 2);
    if (tid < 33) {
      float d = (float)tid - 16.0f;
      g[tid] = expf(-(d * d) * (1.0f / 32.0f));
    }
    if (tid < 140) {
      const int i = tid / 28, cc = tid - i * 28;
      u64 p = packed[(size_t)b * 784 + (rc0 + i) * 28 + cc];
      float d2 = __uint_as_float((unsigned)(p >> 32));
      rows[i][cc] = sqrtf(fmaxf(d2, 1e-12f));
    }
    __syncthreads();
    if (tid == 0) {
      float s = 0.0f;
      for (int t = 0; t < 33; ++t) s += g[t];
      ds[0] = 1.0f / (s * s);
    }
    if (tid < 40) {
      const int dy = tid / 5, i = tid - dy * 5;
      const int y = q * 8 + dy;
      float acc = 0.0f;
      for (int t = 0; t < 33; ++t) {
        int yy = y + t - 16;
        yy = yy < 0 ? -yy : (yy > 223 ? 446 - yy : yy);
        acc += ((yy >> 3) - rc0 == i) ? g[t] : 0.0f;
      }
      gvs[dy][i] = acc;
    }
    __syncthreads();
    if (tid < 224) {
      float hacc[5];
#pragma unroll
      for (int i = 0; i < 5; ++i) hacc[i] = 0.0f;
      for (int s = 0; s < 33; ++s) {
        int xx = tid + s - 16;
        xx = xx < 0 ? -xx : (xx > 223 ? 446 - xx : xx);
        const int cs = xx >> 3;
        const float gs_ = g[s];
#pragma unroll
        for (int i = 0; i < 5; ++i) hacc[i] += gs_ * rows[i][cs];
      }
      const float ginv = ds[0];
#pragma unroll
      for (int dy = 0; dy < 8; ++dy) {
        float acc = 0.0f;
#pragma unroll
        for (int i = 0; i < 5; ++i) acc += gvs[dy][i] * hacc[i];
        out[((size_t)b * 224 + q * 8 + dy) * 224 + tid] = acc * ginv;
      }
    }
    return;
  }

  // ---------------- rescore path: chunk c = blockIdx.x ----------------
  const int c = blockIdx.x;

  // argmax over packed d2 (first occurrence), every block re-derives
  {
    float bv = -INFINITY;
    int bi_ = 0x7fffffff, bl = 0;
    for (int i = tid; i < 784; i += 256) {
      u64 p = packed[(size_t)b * 784 + i];
      float v = __uint_as_float((unsigned)(p >> 32));
      if (v > bv) { bv = v; bi_ = i; bl = (int)(unsigned)p; }
    }
    sv[tid] = bv; si[tid] = bi_; sl[tid] = bl;
    __syncthreads();
    for (int s = 128; s > 0; s >>= 1) {
      if (tid < s) {
        if (sv[tid + s] > sv[tid] ||
            (sv[tid + s] == sv[tid] && si[tid + s] < si[tid])) {
          sv[tid] = sv[tid + s]; si[tid] = si[tid + s]; sl[tid] = sl[tid + s];
        }
      }
      __syncthreads();
    }
  }
  const int nn = sl[0];
  if (c == 0 && tid == 0) {
    score[b] = sqrtf(fmaxf(sv[0], 1e-12f));
    maxrow[b] = b * 784 + si[0];
  }
  __syncthreads();

  if (tid < 16) {
    short8 v = ((const short8*)(Bbf + (size_t)nn * C))[tid];
#pragma unroll
    for (int e = 0; e < 8; ++e) vecf[tid * 8 + e] = bf2f(v[e]);
  }
  __syncthreads();
  const float nnorm = bnorm[nn];
  const int j0 = c * (M >> 5);          // 512 rows per chunk
  float rv[2];
  int rj[2];
#pragma unroll
  for (int q = 0; q < 2; ++q) {
    const int j = j0 + q * 256 + tid;
    const short8* br = (const short8*)(Bbf + (size_t)j * C);
    float dot = 0.0f;
#pragma unroll
    for (int kc = 0; kc < 16; ++kc) {
      short8 v = br[kc];
      float4 w0 = *(const float4*)&vecf[kc * 8];
      float4 w1 = *(const float4*)&vecf[kc * 8 + 4];
      dot += bf2f(v[0]) * w0.x + bf2f(v[1]) * w0.y + bf2f(v[2]) * w0.z +
             bf2f(v[3]) * w0.w + bf2f(v[4]) * w1.x + bf2f(v[5]) * w1.y +
             bf2f(v[6]) * w1.z + bf2f(v[7]) * w1.w;
    }
    rv[q] = nnorm + bnorm[j] - 0.5f * dot;   // Bbf = -2*bank: dot_bf = 4*dot
    rj[q] = j;
  }
  for (int s9 = 0; s9 < 9; ++s9) {
    float bv = INFINITY;
    int bj = 0x7fffffff;
#pragma unroll
    for (int q = 0; q < 2; ++q)
      if (rv[q] < bv) { bv = rv[q]; bj = rj[q]; }
    sv[tid] = bv; si[tid] = bj;
    __syncthreads();
    for (int s = 128; s > 0; s >>= 1) {
      if (tid < s) {
        if (sv[tid + s] < sv[tid] ||
            (sv[tid + s] == sv[tid] && si[tid + s] < si[tid])) {
          sv[tid] = sv[tid + s]; si[tid] = si[tid + s];
        }
      }
      __syncthreads();
    }
    const int selj = si[0];
    if (tid == 0) {
      cvals[((size_t)b * 32 + c) * 9 + s9] = sv[0];
      cidx[((size_t)b * 32 + c) * 9 + s9] = selj;
    }
#pragma unroll
    for (int q = 0; q < 2; ++q)
      if (rj[q] == selj) rv[q] = INFINITY;
    __syncthreads();
  }

  // completion: last chunk-block for this image merges all 288 candidates
  if (tid == 0) {
    __threadfence();                    // release candidate writes
    sl[0] = atomicAdd(&cnt[b], 1);
  }
  __syncthreads();
  if (sl[0] != 31) return;
  __threadfence();                      // acquire all chunks' writes

  for (int i = tid; i < 288; i += 256) {
    wv[i] = cvals[(size_t)b * 288 + i];
    wi[i] = cidx[(size_t)b * 288 + i];
  }
  if (tid < 32)
    *(float4*)&vecf[tid * 4] =
        *(const float4*)(emb + (size_t)maxrow[b] * C + tid * 4);
  __syncthreads();
  for (int s9 = 0; s9 < 9; ++s9) {
    float bv = INFINITY;
    int bi_ = 0x7fffffff, bp = -1;
    for (int i = tid; i < 288; i += 256) {
      if (wv[i] < bv || (wv[i] == bv && wi[i] < bi_)) {
        bv = wv[i]; bi_ = wi[i]; bp = i;
      }
    }
    sv[tid] = bv; si[tid] = bi_; sp[tid] = bp;
    __syncthreads();
    for (int s = 128; s > 0; s >>= 1) {
      if (tid < s) {
        if (sv[tid + s] < sv[tid] ||
            (sv[tid + s] == sv[tid] && si[tid + s] < si[tid])) {
          sv[tid] = sv[tid + s]; si[tid] = si[tid + s]; sp[tid] = sp[tid + s];
        }
      }
      __syncthreads();
    }
    if (tid == 0) {
      sup[s9] = si[0];
      wv[sp[0]] = INFINITY;
    }
    __syncthreads();
  }
  const int w = tid >> 6, lane = tid & 63;
  for (int s = w; s < 9; s += 4) {
    const float* br = Bk + (size_t)sup[s] * C;
    float d0 = vecf[lane * 2] - br[lane * 2];
    float d1 = vecf[lane * 2 + 1] - br[lane * 2 + 1];
    float acc = d0 * d0 + d1 * d1;
#pragma unroll
    for (int m = 1; m <= 32; m <<= 1) acc += __shfl_xor(acc, m, 64);
    if (lane == 0) ds[s] = sqrtf(fmaxf(acc, 1e-12f));
  }
  __syncthreads();
  if (tid == 0) {
    float m = ds[0];
    for (int t = 1; t < 9; ++t) m = fmaxf(m, ds[t]);
    float sum = 0.0f, e0 = 0.0f;
    for (int t = 0; t < 9; ++t) {
      float e = expf(ds[t] - m);
      sum += e;
      if (t == 0) e0 = e;
    }
    pred[b] = (1.0f - e0 / sum) * score[b];
  }
}

// ---------------------------------------------------------------------------
extern "C" void kernel_launch(void* const* d_in, const int* in_sizes, int n_in,
                              void* d_out, int out_size, void* d_ws,
                              size_t ws_size, hipStream_t stream) {
  const float* emb = (const float*)d_in[0];
  const float* bank = (const float*)d_in[1];
  const int N = in_sizes[0] / C;  // 12544
  const int M = in_sizes[1] / C;  // 16384
  const int B = 16;

  u16* Abf = (u16*)d_ws;                          // N*C bf16
  u16* Bbf = Abf + (size_t)N * C;                 // M*C bf16 (scaled -2)
  u64* packed = (u64*)(Bbf + (size_t)M * C);      // N   (8B-aligned)
  float* anorm = (float*)(packed + N);            // N
  float* bnorm = anorm + N;                       // M
  float* score = bnorm + M;                       // B
  int* maxrow = (int*)(score + B);                // B
  float* cvals = (float*)(maxrow + B);            // B*288
  int* cidx = (int*)(cvals + B * 288);            // B*288
  int* cnt = cidx + B * 288;                      // B

  float* out_map = (float*)d_out;
  float* out_pred = out_map + (size_t)B * 224 * 224;

  const int total = (N + M) * (C / 8);
  prep_kernel<<<(total + 255) / 256, 256, 0, stream>>>(
      emb, bank, Abf, Bbf, anorm, bnorm, packed, cnt, N, M);
  nn_mfma<<<(N / 128) * 16, 256, 0, stream>>>(Abf, Bbf, bnorm, anorm, packed,
                                              N, M);
  post_kernel<<<dim3(60, B), 256, 0, stream>>>(Bbf, bnorm, packed, emb, bank,
                                               score, maxrow, cvals, cidx,
                                               cnt, out_pred, out_map, M);
}